// Round 1
// 64.874 us; speedup vs baseline: 1.0134x; 1.0134x over previous
//
#include <hip/hip_runtime.h>
#include <math.h>

// VariationalQuantumAttention — maximally reduced form.
//
// Reduction chain (all exact algebra, no approximation):
//  (A) Key register + W_int cancel: CRY(q_i->k_i) never mixes query basis
//      states, CRZ(k_i->q_i) is diagonal, and ||M_x psi_k|| = 1 for every
//      query basis state x. So P(q0=0,q1=0) depends only on the 4-qubit
//      query circuit. (Established in the previous session.)
//  (B) Layer-2 RZ gates: each commutes with the remaining layer-2 RYs
//      (disjoint wires), so all four can be moved to directly before the
//      final CNOT chain. Diagonal phases followed only by a basis
//      permutation and a probability measurement are unobservable. Drop.
//  (C) Layer-2 CNOT chain: a basis permutation; the preimage of the
//      measured set {j : wire0=wire1=0} = {0,1,2,3} under
//      CNOT(2,3)∘CNOT(1,2)∘CNOT(0,1) is {0,1,3,2} — the same set. The
//      probability sum is invariant. Drop.
//  (D) Layer-2 RY on wires 2,3: act on bits (1,0) only, i.e. they map the
//      measured block (b3=b2=0) unitarily onto itself, preserving its
//      total probability. Drop.
//  => Layer 2 = RY(q0*pi + Wqy[1][0]) on wire 0, RY(q1*pi + Wqy[1][1]) on
//     wire 1, and we only need the bit=0 output components:
//       a''[j] = c1*(c0*a[j] - s0*a[j+8]) - s1*(c0*a[j+4] - s0*a[j+12])
//     for j = 0..3;  P = sum |a''[j]|^2.
//
// Layer 1 remains the full 4-wire circuit (16 complex amps in registers,
// fully unrolled; initial-state sparsity is const-folded by LLVM since
// everything is SSA after unrolling).
// Wire w -> bit position (3 - w) in the flattened index (wire 0 = MSB).

// tanh via exp: tanh(x) = 1 - 2/(e^{2x}+1). v_exp_f32 + v_rcp_f32.
__device__ __forceinline__ float fast_tanh(float x) {
    const float e = __expf(2.0f * x);
    return 1.0f - 2.0f / (e + 1.0f);
}

__global__ __launch_bounds__(256) void vqa_query_kernel(
    const float* __restrict__ query,   // [B][64], only first 4 cols used
    const float* __restrict__ Wqy,     // [2][4]
    const float* __restrict__ Wqz,     // [2][4]
    float* __restrict__ out,           // [B]
    int B)
{
    const int b = blockIdx.x * blockDim.x + threadIdx.x;
    if (b >= B) return;

    // One float4 load per row (16 B used of each 256 B row).
    const float4 qv = *reinterpret_cast<const float4*>(query + (size_t)b * 64);
    float qf[4];
    qf[0] = fast_tanh(qv.x);
    qf[1] = fast_tanh(qv.y);
    qf[2] = fast_tanh(qv.z);
    qf[3] = fast_tanh(qv.w);

    // 16 complex amplitudes, fully unrolled -> registers.
    float sr[16], si[16];
#pragma unroll
    for (int j = 0; j < 16; ++j) { sr[j] = 0.0f; si[j] = 0.0f; }
    sr[0] = 1.0f;

    const float PI = 3.14159265358979323846f;

    // ---------------- Layer 1: full circuit ----------------
#pragma unroll
    for (int i = 0; i < 4; ++i) {
        const int str = 1 << (3 - i);   // bit position of wire i

        // RY(q_i*pi) then RY(W_q_y) == RY(q_i*pi + W_q_y).
        const float half = 0.5f * (qf[i] * PI + Wqy[i]);
        float c, s;
        __sincosf(half, &s, &c);
#pragma unroll
        for (int base = 0; base < 16; ++base) {
            if (base & str) continue;
            const int j0 = base, j1 = base | str;
            const float a0r = sr[j0], a0i = si[j0];
            const float a1r = sr[j1], a1i = si[j1];
            sr[j0] = c * a0r - s * a1r;  si[j0] = c * a0i - s * a1i;
            sr[j1] = s * a0r + c * a1r;  si[j1] = s * a0i + c * a1i;
        }

        // RZ(t): bit=0 amp *= e^{-i t/2}; bit=1 amp *= e^{+i t/2}.
        const float hz = 0.5f * Wqz[i];
        float cz, sz;
        __sincosf(hz, &sz, &cz);
#pragma unroll
        for (int j = 0; j < 16; ++j) {
            const float ar = sr[j], ai = si[j];
            if (j & str) { sr[j] = ar * cz - ai * sz; si[j] = ai * cz + ar * sz; }
            else         { sr[j] = ar * cz + ai * sz; si[j] = ai * cz - ar * sz; }
        }
    }

    // Layer-1 CNOT chain: pure register permutation (free after unroll).
#pragma unroll
    for (int i = 0; i < 3; ++i) {
        const int cb = 1 << (3 - i);
        const int tb = 1 << (2 - i);
#pragma unroll
        for (int j = 0; j < 16; ++j) {
            if ((j & cb) && !(j & tb)) {
                const int j2 = j | tb;
                float t;
                t = sr[j]; sr[j] = sr[j2]; sr[j2] = t;
                t = si[j]; si[j] = si[j2]; si[j2] = t;
            }
        }
    }

    // ---------------- Layer 2: reduced to two RYs ----------------
    // Only the measured block (indices 0..3) of the output is needed.
    const float h0 = 0.5f * (qf[0] * PI + Wqy[4 + 0]);
    const float h1 = 0.5f * (qf[1] * PI + Wqy[4 + 1]);
    float c0, s0, c1, s1;
    __sincosf(h0, &s0, &c0);
    __sincosf(h1, &s1, &c1);

    float p00 = 0.0f;
#pragma unroll
    for (int j = 0; j < 4; ++j) {
        // RY on wire 0 (bit 3), bit=0 components at j and j+4:
        const float ar0 = c0 * sr[j]     - s0 * sr[j + 8];
        const float ai0 = c0 * si[j]     - s0 * si[j + 8];
        const float ar4 = c0 * sr[j + 4] - s0 * sr[j + 12];
        const float ai4 = c0 * si[j + 4] - s0 * si[j + 12];
        // RY on wire 1 (bit 2), bit=0 component:
        const float br = c1 * ar0 - s1 * ar4;
        const float bi = c1 * ai0 - s1 * ai4;
        p00 += br * br + bi * bi;
    }
    out[b] = p00;
}

extern "C" void kernel_launch(void* const* d_in, const int* in_sizes, int n_in,
                              void* d_out, int out_size, void* d_ws, size_t ws_size,
                              hipStream_t stream) {
    const float* query = (const float*)d_in[0];
    // d_in[1] = key      (unused — proven irrelevant)
    const float* Wqy   = (const float*)d_in[2];
    const float* Wqz   = (const float*)d_in[3];
    // d_in[4] = W_k_y, d_in[5] = W_k_z, d_in[6] = W_int (all unused)
    float* out = (float*)d_out;

    const int B = in_sizes[0] / 64;   // feature dim D = 64 per reference

    const int block = 256;
    const int grid = (B + block - 1) / block;
    vqa_query_kernel<<<grid, block, 0, stream>>>(query, Wqy, Wqz, out, B);
}

// Round 2
// 64.225 us; speedup vs baseline: 1.0236x; 1.0101x over previous
//
#include <hip/hip_runtime.h>
#include <math.h>

// VariationalQuantumAttention — closed-form 2-qubit reduction.
//
// Reduction chain (all exact algebra, no approximation):
//  (A) Key register + W_int cancel: CRY(q_i->k_i) never mixes query basis
//      states, CRZ(k_i->q_i) is diagonal, and ||M_x psi_k|| = 1 for every
//      query basis state x. P(q0=0,q1=0) depends only on the query circuit.
//  (B) Layer-2 RZs commute to just before the layer-2 CNOT chain; diagonal
//      phases followed by a permutation + diagonal measurement are
//      unobservable. Drop.
//  (C) Layer-2 CNOT chain: preimage of the measured set {wire0=wire1=0}
//      under CNOT(0,1),(1,2),(2,3) is the same set. Drop.
//  (D) Layer-2 RYs on wires 2,3 act unitarily inside the measured block
//      (sum over wires 2,3). Drop.
//  (E) NEW: measurement involves only wires 0,1 -> trace out wires 2,3.
//      - CNOT(2,3) is unitary on the traced pair: no effect on wires 0,1.
//      - CNOT(1,2) with wire 2 in pure product state psi2 = dephasing
//        channel on wire 1 with factor eta = <psi2|X|psi2>
//                                          = sin(Theta2) * cos(phi2).
//      - Wire 3 drops out of the problem entirely.
//  (F) The remaining 2-qubit computation expands to a closed form in which
//      every RZ angle phi_i = Wqz[0][i] appears only inside
//      cos(phi0), cos(phi1), cos(phi0 +/- phi1), cos(phi2) — all
//      weight-only and thread-uniform.
//
// Per-thread data-dependent work: 3 tanh + 5 sincos + ~40 FLOPs.
//
//   Theta_i = tanh(q_i)*pi + Wqy[0][i]   (i = 0,1,2; layer-1 RY, fused)
//   alpha_i = tanh(q_i)*pi + Wqy[1][i]   (i = 0,1;   layer-2 RY, fused)
//   c_i = cos(Theta_i/2), s_i = sin(Theta_i/2)
//   A0 = cos(alpha0/2), A1 = -sin(alpha0/2)
//   B0 = cos(alpha1/2), B1 = -sin(alpha1/2)
//   P0 = A0*c0*c1, P1 = A1*s0*s1, Q0 = A0*c0*s1, Q1 = A1*s0*c1
//   eta = 2*c2*s2*cos(phi2)
//   P(00) = B0^2*(P0^2 + P1^2 + 2*P0*P1*cos(phi0+phi1))
//         + B1^2*(Q0^2 + Q1^2 + 2*Q0*Q1*cos(phi0-phi1))
//         + 2*eta*B0*B1*((P0*Q0+P1*Q1)*cos(phi1) + (P0*Q1+P1*Q0)*cos(phi0))

// tanh via exp: tanh(x) = 1 - 2/(e^{2x}+1). v_exp_f32 + v_rcp_f32.
__device__ __forceinline__ float fast_tanh(float x) {
    const float e = __expf(2.0f * x);
    return 1.0f - 2.0f / (e + 1.0f);
}

__global__ __launch_bounds__(256) void vqa_query_kernel(
    const float* __restrict__ query,   // [B][64], only first 3 cols used
    const float* __restrict__ Wqy,     // [2][4]
    const float* __restrict__ Wqz,     // [2][4]
    float* __restrict__ out,           // [B]
    int B)
{
    const int b = blockIdx.x * blockDim.x + threadIdx.x;
    if (b >= B) return;

    // One float4 load per row (12 B used of each 256 B row).
    const float4 qv = *reinterpret_cast<const float4*>(query + (size_t)b * 64);

    const float PI = 3.14159265358979323846f;
    const float q0 = fast_tanh(qv.x) * PI;
    const float q1 = fast_tanh(qv.y) * PI;
    const float q2 = fast_tanh(qv.z) * PI;

    // Thread-uniform weight trig (scalar operands; cheap, uniform).
    const float C0 = __cosf(Wqz[0]);
    const float C1 = __cosf(Wqz[1]);
    const float Cp = __cosf(Wqz[0] + Wqz[1]);
    const float Cm = __cosf(Wqz[0] - Wqz[1]);
    const float C2 = __cosf(Wqz[2]);

    // Layer-1 RY half-angles (q rotation fused with weight rotation).
    float c0, s0, c1, s1, c2, s2;
    __sincosf(0.5f * (q0 + Wqy[0]), &s0, &c0);
    __sincosf(0.5f * (q1 + Wqy[1]), &s1, &c1);
    __sincosf(0.5f * (q2 + Wqy[2]), &s2, &c2);

    // Layer-2 RY half-angles, wires 0 and 1.
    float A0, A1n, B0, B1n;
    __sincosf(0.5f * (q0 + Wqy[4]), &A1n, &A0);   // A1 = -A1n
    __sincosf(0.5f * (q1 + Wqy[5]), &B1n, &B0);   // B1 = -B1n
    const float A1 = -A1n;
    const float B1 = -B1n;

    const float P0 = A0 * c0 * c1;
    const float P1 = A1 * s0 * s1;
    const float Q0 = A0 * c0 * s1;
    const float Q1 = A1 * s0 * c1;

    const float eta = 2.0f * c2 * s2 * C2;   // sin(Theta2) * cos(phi2)

    const float T0 = P0 * P0 + P1 * P1 + 2.0f * P0 * P1 * Cp;  // |t0|^2
    const float T1 = Q0 * Q0 + Q1 * Q1 + 2.0f * Q0 * Q1 * Cm;  // |t1|^2
    const float X  = (P0 * Q0 + P1 * Q1) * C1
                   + (P0 * Q1 + P1 * Q0) * C0;                 // Re(t0*conj(t1))

    out[b] = B0 * B0 * T0 + B1 * B1 * T1 + 2.0f * eta * B0 * B1 * X;
}

extern "C" void kernel_launch(void* const* d_in, const int* in_sizes, int n_in,
                              void* d_out, int out_size, void* d_ws, size_t ws_size,
                              hipStream_t stream) {
    const float* query = (const float*)d_in[0];
    // d_in[1] = key      (unused — proven irrelevant)
    const float* Wqy   = (const float*)d_in[2];
    const float* Wqz   = (const float*)d_in[3];
    // d_in[4] = W_k_y, d_in[5] = W_k_z, d_in[6] = W_int (all unused)
    float* out = (float*)d_out;

    const int B = in_sizes[0] / 64;   // feature dim D = 64 per reference

    const int block = 256;
    const int grid = (B + block - 1) / block;
    vqa_query_kernel<<<grid, block, 0, stream>>>(query, Wqy, Wqz, out, B);
}